// Round 9
// baseline (989.065 us; speedup 1.0000x reference)
//
#include <hip/hip_runtime.h>
#include <hip/hip_cooperative_groups.h>
#include <math.h>

namespace cg = cooperative_groups;

#define MTOT 8192   // B*N
#define HD   512    // hidden dim
#define NEG  0.2f   // leaky relu slope

typedef __attribute__((ext_vector_type(8))) short bf16x8;
typedef __attribute__((ext_vector_type(4))) float floatx4;

__device__ inline unsigned short f2bf(float f) {
    unsigned int u = __float_as_uint(f);
    unsigned int r = (u + 0x7FFFu + ((u >> 16) & 1u)) >> 16;
    return (unsigned short)r;
}
__device__ inline float bf2f(unsigned short h) {
    return __uint_as_float(((unsigned int)h) << 16);
}

struct GParams {
    const float* x0;
    const int* esrc; const int* edst; int E;
    const float* W6[6];                  // Wl0,Wr0,Wl1,Wr1,Wl2,Wr2
    const float* bl[3]; const float* br[3];
    const float* av[3]; const float* bs[3];
    unsigned short* Ahi; unsigned short* Alo;
    unsigned short* wtbase;
    float* xl; float* xr;
    int* deg; int* offs; int* cursor; int* csr;
    float* out;
};

// ================= cooperative mega-kernel =================
// 512 blocks x 512 threads, 2 blocks/CU co-resident (VGPR<=128, LDS 32KB).
// Phases: prep -> CSR(count/scan/scatter) -> 3x(GEMM -> aggregate), grid.sync between.

__global__ __launch_bounds__(512, 4) void gat_mega(GParams P) {
    cg::grid_group grid = cg::this_grid();
    __shared__ __align__(16) unsigned char smem[32768];
    const size_t SZ = (size_t)HD * HD;

    int bid = blockIdx.x;
    int tid = threadIdx.x;
    int wave = tid >> 6, lane = tid & 63;

    // ---- P0a: weight transpose+split (1536 32x32-tile tasks, 2 teams/block) ----
    {
        int team = tid >> 8;            // 0,1
        int ttid = tid & 255;
        float (*tt)[33] = (float(*)[33])(smem + team * 4352);
        int tx = ttid & 31, ty = ttid >> 5;   // ty 0..7
        #pragma unroll
        for (int r = 0; r < 2; ++r) {
            int task = bid * 2 + team + r * 1024;
            bool act = task < 1536;
            int zm = act ? (task >> 8) : 0;
            int tile = task & 255;
            int bx = (tile & 15) * 32, by = (tile >> 4) * 32;
            if (act) {
                const float* W = P.W6[zm];
                for (int i = ty; i < 32; i += 8)
                    tt[i][tx] = W[(size_t)(by + i) * HD + bx + tx];
            }
            __syncthreads();
            if (act) {
                int L = zm >> 1, lr2 = zm & 1;
                unsigned short* Whi = P.wtbase + (size_t)(L * 4 + lr2 * 2) * SZ;
                unsigned short* Wlo = Whi + SZ;
                for (int i = ty; i < 32; i += 8) {
                    float vv = tt[tx][i];
                    unsigned short h = f2bf(vv);
                    unsigned short l = f2bf(vv - bf2f(h));
                    Whi[(size_t)(bx + i) * HD + by + tx] = h;
                    Wlo[(size_t)(bx + i) * HD + by + tx] = l;
                }
            }
            __syncthreads();
        }
    }
    // ---- P0b: activation split (1,048,576 float4s over 262,144 threads) ----
    {
        int t0 = bid * 512 + tid;
        #pragma unroll
        for (int u = 0; u < 4; ++u) {
            int i = (t0 + u * 262144) * 4;
            float4 vv = *(const float4*)(P.x0 + i);
            ushort4 h, l;
            h.x = f2bf(vv.x); l.x = f2bf(vv.x - bf2f(h.x));
            h.y = f2bf(vv.y); l.y = f2bf(vv.y - bf2f(h.y));
            h.z = f2bf(vv.z); l.z = f2bf(vv.z - bf2f(h.z));
            h.w = f2bf(vv.w); l.w = f2bf(vv.w - bf2f(h.w));
            *(ushort4*)(P.Ahi + i) = h;
            *(ushort4*)(P.Alo + i) = l;
        }
        // P0c: zero deg
        if (t0 < MTOT) P.deg[t0] = 0;
    }
    grid.sync();

    // ---- P1: count degrees ----
    for (int i = bid * 512 + tid; i < P.E; i += 262144)
        atomicAdd(&P.deg[P.edst[i]], 1);
    grid.sync();

    // ---- P2: exclusive scan (block 0 only; 512 thr x 16 elems) ----
    if (bid == 0) {
        int* part = (int*)smem;
        int base = tid * 16;
        int v[16]; int s = 0;
        #pragma unroll
        for (int i = 0; i < 16; ++i) { v[i] = P.deg[base + i]; s += v[i]; }
        part[tid] = s;
        __syncthreads();
        for (int off = 1; off < 512; off <<= 1) {
            int t = (tid >= off) ? part[tid - off] : 0;
            __syncthreads();
            part[tid] += t;
            __syncthreads();
        }
        int run = tid ? part[tid - 1] : 0;
        #pragma unroll
        for (int i = 0; i < 16; ++i) {
            P.offs[base + i] = run;
            P.cursor[base + i] = run;
            run += v[i];
        }
        if (tid == 511) P.offs[MTOT] = run;
    }
    grid.sync();

    // ---- P3: scatter edges ----
    for (int i = bid * 512 + tid; i < P.E; i += 262144) {
        int d = P.edst[i];
        int p = atomicAdd(&P.cursor[d], 1);
        P.csr[p] = P.esrc[i];
    }
    grid.sync();

    // ---- layers ----
    for (int L = 0; L < 3; ++L) {
        // ===== GEMM phase: 512 tiles (64 m x 4 n x 2 z), 1 tile/block =====
        {
            unsigned short* lds = (unsigned short*)smem;
            int z  = bid & 1;
            int tn = (bid >> 1) & 3;
            int tm = bid >> 3;
            const unsigned short* Bhi = P.wtbase + (size_t)(L * 4 + z * 2) * SZ;
            const unsigned short* Blo = Bhi + SZ;
            const float* bias = z ? P.br[L] : P.bl[L];
            float* C          = z ? P.xr : P.xl;
            int bm = tm * 128, bn = tn * 128;

            const unsigned short* gsrc4[4] = {P.Ahi, P.Alo, Bhi, Blo};
            int rowb4[4] = {bm, bm, bn, bn};
            int twv = wave >> 1, half = wave & 1;
            const unsigned short* gbase =
                gsrc4[twv] + (size_t)(rowb4[twv] + half * 64 + (lane >> 2)) * 512 + (lane & 3) * 8;

            floatx4 acc[4][2] = {};
            int wm2 = wave & 1, wn4 = wave >> 1;   // m-half, n-quarter
            int lr = lane & 15, lq = lane >> 4;

            for (int k0 = 0; k0 < 512; k0 += 32) {
                const unsigned short* g = gbase + k0;
                #pragma unroll
                for (int rg = 0; rg < 4; ++rg) {
                    __builtin_amdgcn_global_load_lds(
                        (const __attribute__((address_space(1))) unsigned int*)(g + (size_t)rg * 16 * 512),
                        (__attribute__((address_space(3))) unsigned int*)(&lds[twv * 4096 + half * 2048 + rg * 512]),
                        16, 0, 0);
                }
                __syncthreads();

                bf16x8 ah[4], al[4], bh[2], bl_[2];
                #pragma unroll
                for (int i = 0; i < 4; ++i) {
                    int mrow = wm2 * 64 + i * 16 + lr;
                    ah[i] = *(const bf16x8*)&lds[0 * 4096 + mrow * 32 + lq * 8];
                    al[i] = *(const bf16x8*)&lds[1 * 4096 + mrow * 32 + lq * 8];
                }
                #pragma unroll
                for (int j = 0; j < 2; ++j) {
                    int nrow = wn4 * 32 + j * 16 + lr;
                    bh[j]  = *(const bf16x8*)&lds[2 * 4096 + nrow * 32 + lq * 8];
                    bl_[j] = *(const bf16x8*)&lds[3 * 4096 + nrow * 32 + lq * 8];
                }
                #pragma unroll
                for (int i = 0; i < 4; ++i)
                    #pragma unroll
                    for (int j = 0; j < 2; ++j) {
                        acc[i][j] = __builtin_amdgcn_mfma_f32_16x16x32_bf16(ah[i], bh[j],  acc[i][j], 0, 0, 0);
                        acc[i][j] = __builtin_amdgcn_mfma_f32_16x16x32_bf16(ah[i], bl_[j], acc[i][j], 0, 0, 0);
                        acc[i][j] = __builtin_amdgcn_mfma_f32_16x16x32_bf16(al[i], bh[j],  acc[i][j], 0, 0, 0);
                    }
                __syncthreads();
            }

            #pragma unroll
            for (int j = 0; j < 2; ++j) {
                int n = bn + wn4 * 32 + j * 16 + lr;
                float bv = bias[n];
                #pragma unroll
                for (int i = 0; i < 4; ++i) {
                    int mb = bm + wm2 * 64 + i * 16 + lq * 4;
                    #pragma unroll
                    for (int r = 0; r < 4; ++r)
                        C[(size_t)(mb + r) * 512 + n] = acc[i][j][r] + bv;
                }
            }
        }
        grid.sync();

        // ===== aggregate phase: 16 nodes/block, wave-per-node (2 each) =====
        {
            int write_fp32 = (L == 2);
            const float* avec = P.av[L];
            const float* bias = P.bs[L];
            float* sc = (float*)smem + wave * 128;   // wave-private 128 floats
            int nbase = ((bid & 7) << 10) + ((bid >> 3) << 4);

            for (int nn = wave; nn < 16; nn += 8) {
                int node = nbase + nn;
                int beg = P.offs[node], end = P.offs[node + 1];
                int dg = end - beg;
                if (dg > 128) dg = 128;

                // phase 1: edge scores (16 lanes/edge, 4 edges/iter)
                {
                    int sub = lane >> 4, flane = lane & 15;
                    float4 avr[8], rv[8];
                    const float* xrrow = P.xr + (size_t)node * HD;
                    #pragma unroll
                    for (int i = 0; i < 8; ++i) {
                        avr[i] = *(const float4*)(avec + i * 64 + flane * 4);
                        rv[i]  = *(const float4*)(xrrow + i * 64 + flane * 4);
                    }
                    for (int p0 = 0; p0 < dg; p0 += 4) {
                        int p = p0 + sub;
                        bool valid = p < dg;
                        int j = P.csr[beg + (valid ? p : 0)];
                        const float* xls = P.xl + (size_t)j * HD;
                        float pe = 0.f;
                        #pragma unroll
                        for (int i = 0; i < 8; ++i) {
                            float4 xv = *(const float4*)(xls + i * 64 + flane * 4);
                            float t;
                            t = xv.x + rv[i].x; pe += avr[i].x * (t > 0.f ? t : NEG * t);
                            t = xv.y + rv[i].y; pe += avr[i].y * (t > 0.f ? t : NEG * t);
                            t = xv.z + rv[i].z; pe += avr[i].z * (t > 0.f ? t : NEG * t);
                            t = xv.w + rv[i].w; pe += avr[i].w * (t > 0.f ? t : NEG * t);
                        }
                        pe += __shfl_xor(pe, 1, 64);
                        pe += __shfl_xor(pe, 2, 64);
                        pe += __shfl_xor(pe, 4, 64);
                        pe += __shfl_xor(pe, 8, 64);
                        if (valid && flane == 0) sc[p] = pe;
                    }
                }

                // phase 2: softmax (wave-local)
                float s0v = (lane < dg) ? sc[lane] : -1e30f;
                float s1v = (lane + 64 < dg) ? sc[lane + 64] : -1e30f;
                float m = fmaxf(s0v, s1v);
                #pragma unroll
                for (int off = 32; off; off >>= 1) m = fmaxf(m, __shfl_xor(m, off, 64));
                float e0 = (lane < dg) ? __expf(s0v - m) : 0.f;
                float e1 = (lane + 64 < dg) ? __expf(s1v - m) : 0.f;
                if (lane < dg) sc[lane] = e0;
                if (lane + 64 < dg) sc[lane + 64] = e1;
                float s = e0 + e1;
                #pragma unroll
                for (int off = 32; off; off >>= 1) s += __shfl_xor(s, off, 64);
                float inv = (s > 0.f) ? 1.f / s : 0.f;

                // phase 3: weighted gather (ILP-4)
                int h0 = lane << 2;
                float4 acc0 = {0.f, 0.f, 0.f, 0.f}, acc1 = {0.f, 0.f, 0.f, 0.f};
                int p = 0;
                for (; p + 4 <= dg; p += 4) {
                    float w0 = sc[p + 0], w1 = sc[p + 1], w2 = sc[p + 2], w3 = sc[p + 3];
                    int j0 = P.csr[beg + p + 0], j1 = P.csr[beg + p + 1];
                    int j2 = P.csr[beg + p + 2], j3 = P.csr[beg + p + 3];
                    const float* q0 = P.xl + (size_t)j0 * HD;
                    const float* q1 = P.xl + (size_t)j1 * HD;
                    const float* q2 = P.xl + (size_t)j2 * HD;
                    const float* q3 = P.xl + (size_t)j3 * HD;
                    float4 x00 = *(const float4*)(q0 + h0), x01 = *(const float4*)(q0 + 256 + h0);
                    float4 x10 = *(const float4*)(q1 + h0), x11 = *(const float4*)(q1 + 256 + h0);
                    float4 x20 = *(const float4*)(q2 + h0), x21 = *(const float4*)(q2 + 256 + h0);
                    float4 x30 = *(const float4*)(q3 + h0), x31 = *(const float4*)(q3 + 256 + h0);
                    acc0.x += w0 * x00.x + w1 * x10.x + w2 * x20.x + w3 * x30.x;
                    acc0.y += w0 * x00.y + w1 * x10.y + w2 * x20.y + w3 * x30.y;
                    acc0.z += w0 * x00.z + w1 * x10.z + w2 * x20.z + w3 * x30.z;
                    acc0.w += w0 * x00.w + w1 * x10.w + w2 * x20.w + w3 * x30.w;
                    acc1.x += w0 * x01.x + w1 * x11.x + w2 * x21.x + w3 * x31.x;
                    acc1.y += w0 * x01.y + w1 * x11.y + w2 * x21.y + w3 * x31.y;
                    acc1.z += w0 * x01.z + w1 * x11.z + w2 * x21.z + w3 * x31.z;
                    acc1.w += w0 * x01.w + w1 * x11.w + w2 * x21.w + w3 * x31.w;
                }
                for (; p < dg; ++p) {
                    float w = sc[p];
                    int j = P.csr[beg + p];
                    const float* q = P.xl + (size_t)j * HD;
                    float4 x0 = *(const float4*)(q + h0), x1 = *(const float4*)(q + 256 + h0);
                    acc0.x += w * x0.x; acc0.y += w * x0.y; acc0.z += w * x0.z; acc0.w += w * x0.w;
                    acc1.x += w * x1.x; acc1.y += w * x1.y; acc1.z += w * x1.z; acc1.w += w * x1.w;
                }

                float4 b0 = *(const float4*)(bias + h0);
                float4 b1 = *(const float4*)(bias + 256 + h0);
                float4 o0 = {acc0.x * inv + b0.x, acc0.y * inv + b0.y,
                             acc0.z * inv + b0.z, acc0.w * inv + b0.w};
                float4 o1 = {acc1.x * inv + b1.x, acc1.y * inv + b1.y,
                             acc1.z * inv + b1.z, acc1.w * inv + b1.w};

                if (write_fp32) {
                    float* orow = P.out + (size_t)node * HD;
                    *(float4*)(orow + h0) = o0;
                    *(float4*)(orow + 256 + h0) = o1;
                } else {
                    size_t rb = (size_t)node * HD;
                    ushort4 h, lo;
                    h.x = f2bf(o0.x); lo.x = f2bf(o0.x - bf2f(h.x));
                    h.y = f2bf(o0.y); lo.y = f2bf(o0.y - bf2f(h.y));
                    h.z = f2bf(o0.z); lo.z = f2bf(o0.z - bf2f(h.z));
                    h.w = f2bf(o0.w); lo.w = f2bf(o0.w - bf2f(h.w));
                    *(ushort4*)(P.Ahi + rb + h0) = h;
                    *(ushort4*)(P.Alo + rb + h0) = lo;
                    h.x = f2bf(o1.x); lo.x = f2bf(o1.x - bf2f(h.x));
                    h.y = f2bf(o1.y); lo.y = f2bf(o1.y - bf2f(h.y));
                    h.z = f2bf(o1.z); lo.z = f2bf(o1.z - bf2f(h.z));
                    h.w = f2bf(o1.w); lo.w = f2bf(o1.w - bf2f(h.w));
                    *(ushort4*)(P.Ahi + rb + 256 + h0) = h;
                    *(ushort4*)(P.Alo + rb + 256 + h0) = lo;
                }
            }
        }
        if (L < 2) grid.sync();
    }
}

// ================= fallback path (r8 kernels) =================

__global__ void count_deg(const int* __restrict__ dst, int* __restrict__ deg, int E) {
    int i = blockIdx.x * 256 + threadIdx.x;
    if (i < E) atomicAdd(&deg[dst[i]], 1);
}

__global__ __launch_bounds__(1024) void scan_offsets(const int* __restrict__ deg,
                                                     int* __restrict__ offs,
                                                     int* __restrict__ cursor) {
    __shared__ int part[1024];
    int tid = threadIdx.x;
    int base = tid * 8;
    int v[8]; int s = 0;
    #pragma unroll
    for (int i = 0; i < 8; ++i) { v[i] = deg[base + i]; s += v[i]; }
    part[tid] = s;
    __syncthreads();
    for (int off = 1; off < 1024; off <<= 1) {
        int t = (tid >= off) ? part[tid - off] : 0;
        __syncthreads();
        part[tid] += t;
        __syncthreads();
    }
    int run = (tid == 0) ? 0 : part[tid - 1];
    #pragma unroll
    for (int i = 0; i < 8; ++i) {
        offs[base + i] = run;
        cursor[base + i] = run;
        run += v[i];
    }
    if (tid == 1023) offs[MTOT] = run;
}

__global__ void scatter_edges(const int* __restrict__ src, const int* __restrict__ dst,
                              int* __restrict__ cursor, int* __restrict__ csr_src, int E) {
    int i = blockIdx.x * 256 + threadIdx.x;
    if (i < E) {
        int p = atomicAdd(&cursor[dst[i]], 1);
        csr_src[p] = src[i];
    }
}

__global__ __launch_bounds__(256) void prep_convert(
    const float* __restrict__ W0, const float* __restrict__ W1,
    const float* __restrict__ W2, const float* __restrict__ W3,
    const float* __restrict__ W4, const float* __restrict__ W5,
    unsigned short* __restrict__ wtbase,
    const float* __restrict__ X,
    unsigned short* __restrict__ Ahi, unsigned short* __restrict__ Alo,
    int* __restrict__ deg)
{
    int z = blockIdx.z;
    if (z == 7) {
        if (blockIdx.x == 0 && blockIdx.y == 0) {
            for (int i = threadIdx.x; i < MTOT; i += 256) deg[i] = 0;
        }
        return;
    }
    if (z == 6) {
        int bid = blockIdx.x * 16 + blockIdx.y;
        int t0 = bid * 256 + threadIdx.x;
        #pragma unroll
        for (int it = 0; it < 16; ++it) {
            int i = (t0 + it * 65536) * 4;
            float4 vv = *(const float4*)(X + i);
            ushort4 h, l;
            h.x = f2bf(vv.x); l.x = f2bf(vv.x - bf2f(h.x));
            h.y = f2bf(vv.y); l.y = f2bf(vv.y - bf2f(h.y));
            h.z = f2bf(vv.z); l.z = f2bf(vv.z - bf2f(h.z));
            h.w = f2bf(vv.w); l.w = f2bf(vv.w - bf2f(h.w));
            *(ushort4*)(Ahi + i) = h;
            *(ushort4*)(Alo + i) = l;
        }
        return;
    }
    const float* W = (z == 0) ? W0 : (z == 1) ? W1 : (z == 2) ? W2
                   : (z == 3) ? W3 : (z == 4) ? W4 : W5;
    int L = z >> 1, lr = z & 1;
    const size_t SZ = (size_t)HD * HD;
    unsigned short* Whi = wtbase + (L * 4 + lr * 2) * SZ;
    unsigned short* Wlo = Whi + SZ;

    __shared__ float t[32][33];
    int bx = blockIdx.x * 32;
    int by = blockIdx.y * 32;
    int tx = threadIdx.x & 31, ty = threadIdx.x >> 5;
    for (int i = ty; i < 32; i += 8)
        t[i][tx] = W[(size_t)(by + i) * HD + bx + tx];
    __syncthreads();
    for (int i = ty; i < 32; i += 8) {
        float vv = t[tx][i];
        unsigned short h = f2bf(vv);
        unsigned short l = f2bf(vv - bf2f(h));
        Whi[(size_t)(bx + i) * HD + by + tx] = h;
        Wlo[(size_t)(bx + i) * HD + by + tx] = l;
    }
}

__global__ __launch_bounds__(256) void gemm_mfma_dual(
    const unsigned short* __restrict__ Ahi, const unsigned short* __restrict__ Alo,
    const unsigned short* __restrict__ Bhi_l, const unsigned short* __restrict__ Blo_l,
    const unsigned short* __restrict__ Bhi_r, const unsigned short* __restrict__ Blo_r,
    const float* __restrict__ bias_l, const float* __restrict__ bias_r,
    float* __restrict__ Cl, float* __restrict__ Cr)
{
    const unsigned short* Bhi = blockIdx.z ? Bhi_r : Bhi_l;
    const unsigned short* Blo = blockIdx.z ? Blo_r : Blo_l;
    const float* bias         = blockIdx.z ? bias_r : bias_l;
    float* C                  = blockIdx.z ? Cr : Cl;

    __shared__ __align__(16) unsigned short lds[4 * 128 * 32];

    int tid = threadIdx.x;
    int wave = tid >> 6, lane = tid & 63;
    int bm = blockIdx.y * 128, bn = blockIdx.x * 128;

    const unsigned short* gsrc[4] = {Ahi, Alo, Bhi, Blo};
    int rowbase[4] = {bm, bm, bn, bn};

    const unsigned short* gbase =
        gsrc[wave] + (size_t)(rowbase[wave] + (lane >> 2)) * 512 + (lane & 3) * 8;

    floatx4 acc[4][4] = {};

    int wm = wave & 1, wn = wave >> 1;
    int lr = lane & 15, lq = lane >> 4;

    for (int k0 = 0; k0 < 512; k0 += 32) {
        const unsigned short* g = gbase + k0;
        #pragma unroll
        for (int rg = 0; rg < 8; ++rg) {
            __builtin_amdgcn_global_load_lds(
                (const __attribute__((address_space(1))) unsigned int*)(g + (size_t)rg * 16 * 512),
                (__attribute__((address_space(3))) unsigned int*)(&lds[wave * 4096 + rg * 512]),
                16, 0, 0);
        }
        __syncthreads();

        bf16x8 ah[4], al[4], bh[4], bl_[4];
        #pragma unroll
        for (int i = 0; i < 4; ++i) {
            int mrow = wm * 64 + i * 16 + lr;
            ah[i]  = *(const bf16x8*)&lds[0 * 4096 + mrow * 32 + lq * 8];
            al[i]  = *(const bf16x8*)&lds[1 * 4096 + mrow * 32 + lq * 8];
            int nrow = wn * 64 + i * 16 + lr;
            bh[i]  = *(const bf16x8*)&lds[2 * 4096 + nrow * 32 + lq * 8];
            bl_[i] = *(const bf16x8*)&lds[3 * 4096 + nrow * 32 + lq * 8];
        }
        #pragma unroll
        for (int i = 0; i < 4; ++i)
            #pragma unroll
            for (int j = 0; j < 4; ++j) {
                acc[i][j] = __builtin_amdgcn_mfma_f32_16x16x32_bf16(ah[i], bh[j],  acc[i][j], 0, 0, 0);
                acc[i][j] = __builtin_amdgcn_mfma_f32_16x16x32_bf16(ah[i], bl_[j], acc[i][j], 0, 0, 0);
                acc[i][j] = __builtin_amdgcn_mfma_f32_16x16x32_bf16(al[i], bh[j],  acc[i][j], 0, 0, 0);
            }
        __syncthreads();
    }

    #pragma unroll
    for (int j = 0; j < 4; ++j) {
        int n = bn + wn * 64 + j * 16 + lr;
        float bv = bias[n];
        #pragma unroll
        for (int i = 0; i < 4; ++i) {
            int mbase = bm + wm * 64 + i * 16 + lq * 4;
            #pragma unroll
            for (int r = 0; r < 4; ++r)
                C[(size_t)(mbase + r) * 512 + n] = acc[i][j][r] + bv;
        }
    }
}

__global__ __launch_bounds__(512) void gat_fused2(
    const float* __restrict__ xl, const float* __restrict__ xr,
    const float* __restrict__ avec, const float* __restrict__ bias,
    const int* __restrict__ offs, const int* __restrict__ csr_src,
    float* __restrict__ out, unsigned short* __restrict__ Ohi,
    unsigned short* __restrict__ Olo, int write_fp32)
{
    __shared__ float xr_sh[4][512];
    __shared__ float sc_sh[4][128];
    __shared__ float inv_sh[4];

    int gid = blockIdx.x;
    int nbase = ((gid & 7) << 10) + ((gid >> 3) << 2);
    int tid = threadIdx.x;
    int wv = tid >> 6, lane = tid & 63;

    int o0 = offs[nbase], o1 = offs[nbase + 1], o2 = offs[nbase + 2];
    int o3 = offs[nbase + 3], o4 = offs[nbase + 4];

    {
        int row = tid >> 7, col = tid & 127;
        *(float4*)&xr_sh[row][col * 4] =
            *(const float4*)(xr + (size_t)(nbase + row) * HD + col * 4);
    }
    __syncthreads();

    {
        int sub = lane >> 4, flane = lane & 15;
        float4 av[8];
        #pragma unroll
        for (int i = 0; i < 8; ++i)
            av[i] = *(const float4*)(avec + i * 64 + flane * 4);

        for (int p0 = o0 + wv * 4; p0 < o4; p0 += 32) {
            int p = p0 + sub;
            bool valid = p < o4;
            int pc = valid ? p : o0;
            int nid = (pc >= o1) + (pc >= o2) + (pc >= o3);
            int nb = (nid == 0) ? o0 : (nid == 1) ? o1 : (nid == 2) ? o2 : o3;
            int local = pc - nb;
            int j = csr_src[pc];
            const float* xls = xl + (size_t)j * HD;
            float pe = 0.f;
            #pragma unroll
            for (int i = 0; i < 8; ++i) {
                float4 xv = *(const float4*)(xls + i * 64 + flane * 4);
                float4 rv = *(const float4*)&xr_sh[nid][i * 64 + flane * 4];
                float t;
                t = xv.x + rv.x; pe += av[i].x * (t > 0.f ? t : NEG * t);
                t = xv.y + rv.y; pe += av[i].y * (t > 0.f ? t : NEG * t);
                t = xv.z + rv.z; pe += av[i].z * (t > 0.f ? t : NEG * t);
                t = xv.w + rv.w; pe += av[i].w * (t > 0.f ? t : NEG * t);
            }
            pe += __shfl_xor(pe, 1, 64);
            pe += __shfl_xor(pe, 2, 64);
            pe += __shfl_xor(pe, 4, 64);
            pe += __shfl_xor(pe, 8, 64);
            if (valid && flane == 0 && local < 128) sc_sh[nid][local] = pe;
        }
    }
    __syncthreads();

    if (wv < 4) {
        int nb  = (wv == 0) ? o0 : (wv == 1) ? o1 : (wv == 2) ? o2 : o3;
        int ne  = (wv == 0) ? o1 : (wv == 1) ? o2 : (wv == 2) ? o3 : o4;
        int dg = ne - nb; if (dg > 128) dg = 128;
        float s0v = (lane < dg) ? sc_sh[wv][lane] : -1e30f;
        float s1v = (lane + 64 < dg) ? sc_sh[wv][lane + 64] : -1e30f;
        float m = fmaxf(s0v, s1v);
        #pragma unroll
        for (int off = 32; off; off >>= 1) m = fmaxf(m, __shfl_xor(m, off, 64));
        float e0 = (lane < dg) ? __expf(s0v - m) : 0.f;
        float e1 = (lane + 64 < dg) ? __expf(s1v - m) : 0.f;
        if (lane < dg) sc_sh[wv][lane] = e0;
        if (lane + 64 < dg) sc_sh[wv][lane + 64] = e1;
        float s = e0 + e1;
        #pragma unroll
        for (int off = 32; off; off >>= 1) s += __shfl_xor(s, off, 64);
        if (lane == 0) inv_sh[wv] = (s > 0.f) ? 1.f / s : 0.f;
    }
    __syncthreads();

    int nid = wv & 3, half = wv >> 2;
    int node = nbase + nid;
    int nb  = (nid == 0) ? o0 : (nid == 1) ? o1 : (nid == 2) ? o2 : o3;
    int ne  = (nid == 0) ? o1 : (nid == 1) ? o2 : (nid == 2) ? o3 : o4;
    int dg = ne - nb; if (dg > 128) dg = 128;
    int hb = half * 256 + lane * 4;

    float4 acc = {0.f, 0.f, 0.f, 0.f};
    int p = 0;
    for (; p + 8 <= dg; p += 8) {
        float w[8]; const float* q[8];
        #pragma unroll
        for (int u = 0; u < 8; ++u) {
            w[u] = sc_sh[nid][p + u];
            q[u] = xl + (size_t)csr_src[nb + p + u] * HD + hb;
        }
        float4 x[8];
        #pragma unroll
        for (int u = 0; u < 8; ++u) x[u] = *(const float4*)q[u];
        #pragma unroll
        for (int u = 0; u < 8; ++u) {
            acc.x += w[u] * x[u].x; acc.y += w[u] * x[u].y;
            acc.z += w[u] * x[u].z; acc.w += w[u] * x[u].w;
        }
    }
    for (; p < dg; ++p) {
        float w = sc_sh[nid][p];
        const float* q = xl + (size_t)csr_src[nb + p] * HD + hb;
        float4 x = *(const float4*)q;
        acc.x += w * x.x; acc.y += w * x.y; acc.z += w * x.z; acc.w += w * x.w;
    }

    float inv = inv_sh[nid];
    float4 bv = *(const float4*)(bias + hb);
    float4 o = {acc.x * inv + bv.x, acc.y * inv + bv.y,
                acc.z * inv + bv.z, acc.w * inv + bv.w};

    if (write_fp32) {
        *(float4*)(out + (size_t)node * HD + hb) = o;
    } else {
        size_t rb = (size_t)node * HD + hb;
        ushort4 h, lo;
        h.x = f2bf(o.x); lo.x = f2bf(o.x - bf2f(h.x));
        h.y = f2bf(o.y); lo.y = f2bf(o.y - bf2f(h.y));
        h.z = f2bf(o.z); lo.z = f2bf(o.z - bf2f(h.z));
        h.w = f2bf(o.w); lo.w = f2bf(o.w - bf2f(h.w));
        *(ushort4*)(Ohi + rb) = h;
        *(ushort4*)(Olo + rb) = lo;
    }
}

// ---------------- launch ----------------

extern "C" void kernel_launch(void* const* d_in, const int* in_sizes, int n_in,
                              void* d_out, int out_size, void* d_ws, size_t ws_size,
                              hipStream_t stream) {
    const float* x0 = (const float*)d_in[0];
    const int* eidx = (const int*)d_in[2];
    int E = in_sizes[2] / 2;
    const int* esrc = eidx;
    const int* edst = eidx + E;

    const float* Wl[3] = {(const float*)d_in[3],  (const float*)d_in[9],  (const float*)d_in[15]};
    const float* bl[3] = {(const float*)d_in[4],  (const float*)d_in[10], (const float*)d_in[16]};
    const float* Wr[3] = {(const float*)d_in[5],  (const float*)d_in[11], (const float*)d_in[17]};
    const float* br[3] = {(const float*)d_in[6],  (const float*)d_in[12], (const float*)d_in[18]};
    const float* av[3] = {(const float*)d_in[7],  (const float*)d_in[13], (const float*)d_in[19]};
    const float* bs[3] = {(const float*)d_in[8],  (const float*)d_in[14], (const float*)d_in[20]};

    char* w = (char*)d_ws;
    unsigned short* Ahi = (unsigned short*)w; w += (size_t)MTOT * HD * 2;
    unsigned short* Alo = (unsigned short*)w; w += (size_t)MTOT * HD * 2;
    unsigned short* wtbase = (unsigned short*)w; w += 12 * (size_t)HD * HD * 2;
    float* xl = (float*)w; w += (size_t)MTOT * HD * 4;
    float* xr = (float*)w; w += (size_t)MTOT * HD * 4;
    int* deg    = (int*)w;
    int* offs   = deg + MTOT;
    int* cursor = offs + MTOT + 8;
    int* csr    = cursor + MTOT;
    const size_t SZ = (size_t)HD * HD;

    GParams P;
    P.x0 = x0; P.esrc = esrc; P.edst = edst; P.E = E;
    P.W6[0] = Wl[0]; P.W6[1] = Wr[0]; P.W6[2] = Wl[1];
    P.W6[3] = Wr[1]; P.W6[4] = Wl[2]; P.W6[5] = Wr[2];
    for (int i = 0; i < 3; ++i) {
        P.bl[i] = bl[i]; P.br[i] = br[i]; P.av[i] = av[i]; P.bs[i] = bs[i];
    }
    P.Ahi = Ahi; P.Alo = Alo; P.wtbase = wtbase;
    P.xl = xl; P.xr = xr;
    P.deg = deg; P.offs = offs; P.cursor = cursor; P.csr = csr;
    P.out = (float*)d_out;

    void* args[] = {(void*)&P};
    hipError_t err = hipLaunchCooperativeKernel((const void*)gat_mega,
                                                dim3(512), dim3(512), args, 0, stream);
    if (err == hipSuccess) return;

    // ---- deterministic fallback: r8 multi-dispatch path ----
    prep_convert<<<dim3(16, 16, 8), 256, 0, stream>>>(
        Wl[0], Wr[0], Wl[1], Wr[1], Wl[2], Wr[2], wtbase, x0, Ahi, Alo, deg);
    count_deg<<<(E + 255) / 256, 256, 0, stream>>>(edst, deg, E);
    scan_offsets<<<1, 1024, 0, stream>>>(deg, offs, cursor);
    scatter_edges<<<(E + 255) / 256, 256, 0, stream>>>(esrc, edst, cursor, csr, E);

    dim3 ggrid(HD / 128, MTOT / 128, 2);
    for (int L = 0; L < 3; ++L) {
        gemm_mfma_dual<<<ggrid, 256, 0, stream>>>(Ahi, Alo,
            wtbase + (L * 4 + 0) * SZ, wtbase + (L * 4 + 1) * SZ,
            wtbase + (L * 4 + 2) * SZ, wtbase + (L * 4 + 3) * SZ,
            bl[L], br[L], xl, xr);
        int last = (L == 2);
        gat_fused2<<<MTOT / 4, 512, 0, stream>>>(xl, xr, av[L], bs[L], offs, csr,
                                                 last ? (float*)d_out : nullptr,
                                                 last ? nullptr : Ahi,
                                                 last ? nullptr : Alo,
                                                 last);
    }
}

// Round 10
// 481.312 us; speedup vs baseline: 2.0549x; 2.0549x over previous
//
#include <hip/hip_runtime.h>
#include <hip/hip_cooperative_groups.h>
#include <math.h>

namespace cg = cooperative_groups;

#define MTOT 8192   // B*N
#define HD   512    // hidden dim

typedef __attribute__((ext_vector_type(8))) short bf16x8;
typedef __attribute__((ext_vector_type(4))) float floatx4;

__device__ inline unsigned short f2bf(float f) {
    unsigned int u = __float_as_uint(f);
    unsigned int r = (u + 0x7FFFu + ((u >> 16) & 1u)) >> 16;
    return (unsigned short)r;
}
__device__ inline float bf2f(unsigned short h) {
    return __uint_as_float(((unsigned int)h) << 16);
}

// ================= cooperative prep + CSR (1 dispatch) =================
// 256 blocks x 256 threads. grid.sync dirty sets are small (first sync ~30MB,
// rest KB-scale) so the XCD L2 flush cost per sync is low — unlike r9's
// per-layer syncs which flushed the full working set (the 870us lesson).

struct PrepParams {
    const float* W6[6];
    const float* x0;
    unsigned short* wtbase;
    unsigned short* Ahi; unsigned short* Alo;
    const int* esrc; const int* edst; int E;
    int* deg; int* offs; int* cursor; int* csr;
};

__global__ __launch_bounds__(256) void prep_csr(PrepParams P) {
    cg::grid_group grid = cg::this_grid();
    __shared__ float tt[32][33];
    __shared__ int part[256];
    int bid = blockIdx.x, tid = threadIdx.x;
    const size_t SZ = (size_t)HD * HD;

    // P0a: weight transpose+split: 1536 32x32-tile tasks, 6 per block
    #pragma unroll
    for (int r = 0; r < 6; ++r) {
        int task = bid + r * 256;
        int zm = task >> 8;            // 0..5 : Wl0,Wr0,Wl1,Wr1,Wl2,Wr2
        int tile = task & 255;
        int bx = (tile & 15) * 32, by = (tile >> 4) * 32;
        const float* W = P.W6[zm];
        int tx = tid & 31, ty = tid >> 5;
        __syncthreads();
        for (int i = ty; i < 32; i += 8)
            tt[i][tx] = W[(size_t)(by + i) * HD + bx + tx];
        __syncthreads();
        int L = zm >> 1, lr2 = zm & 1;
        unsigned short* Whi = P.wtbase + (size_t)(L * 4 + lr2 * 2) * SZ;
        unsigned short* Wlo = Whi + SZ;
        for (int i = ty; i < 32; i += 8) {
            float vv = tt[tx][i];
            unsigned short h = f2bf(vv);
            unsigned short l = f2bf(vv - bf2f(h));
            Whi[(size_t)(bx + i) * HD + by + tx] = h;
            Wlo[(size_t)(bx + i) * HD + by + tx] = l;
        }
    }
    // P0b: activation split (1M float4 over 65536 threads = 16 each) + deg zero
    {
        int t0 = bid * 256 + tid;
        #pragma unroll
        for (int u = 0; u < 16; ++u) {
            int i = (t0 + u * 65536) * 4;
            float4 vv = *(const float4*)(P.x0 + i);
            ushort4 h, l;
            h.x = f2bf(vv.x); l.x = f2bf(vv.x - bf2f(h.x));
            h.y = f2bf(vv.y); l.y = f2bf(vv.y - bf2f(h.y));
            h.z = f2bf(vv.z); l.z = f2bf(vv.z - bf2f(h.z));
            h.w = f2bf(vv.w); l.w = f2bf(vv.w - bf2f(h.w));
            *(ushort4*)(P.Ahi + i) = h;
            *(ushort4*)(P.Alo + i) = l;
        }
        if (t0 < MTOT) P.deg[t0] = 0;
    }
    grid.sync();

    // P1: count degrees
    for (int i = bid * 256 + tid; i < P.E; i += 65536)
        atomicAdd(&P.deg[P.edst[i]], 1);
    grid.sync();

    // P2: exclusive scan (block 0; 256 thr x 32 elems)
    if (bid == 0) {
        int base = tid * 32;
        int v[32]; int s = 0;
        #pragma unroll
        for (int i = 0; i < 32; ++i) { v[i] = P.deg[base + i]; s += v[i]; }
        part[tid] = s;
        __syncthreads();
        for (int off = 1; off < 256; off <<= 1) {
            int t = (tid >= off) ? part[tid - off] : 0;
            __syncthreads();
            part[tid] += t;
            __syncthreads();
        }
        int run = tid ? part[tid - 1] : 0;
        #pragma unroll
        for (int i = 0; i < 32; ++i) {
            P.offs[base + i] = run;
            P.cursor[base + i] = run;
            run += v[i];
        }
        if (tid == 255) P.offs[MTOT] = run;
    }
    grid.sync();

    // P3: scatter edges
    for (int i = bid * 256 + tid; i < P.E; i += 65536) {
        int d = P.edst[i];
        int p = atomicAdd(&P.cursor[d], 1);
        P.csr[p] = P.esrc[i];
    }
}

// ================= fallback CSR/prep (r8 path) =================

__global__ void count_deg(const int* __restrict__ dst, int* __restrict__ deg, int E) {
    int i = blockIdx.x * 256 + threadIdx.x;
    if (i < E) atomicAdd(&deg[dst[i]], 1);
}

__global__ __launch_bounds__(1024) void scan_offsets(const int* __restrict__ deg,
                                                     int* __restrict__ offs,
                                                     int* __restrict__ cursor) {
    __shared__ int part[1024];
    int tid = threadIdx.x;
    int base = tid * 8;
    int v[8]; int s = 0;
    #pragma unroll
    for (int i = 0; i < 8; ++i) { v[i] = deg[base + i]; s += v[i]; }
    part[tid] = s;
    __syncthreads();
    for (int off = 1; off < 1024; off <<= 1) {
        int t = (tid >= off) ? part[tid - off] : 0;
        __syncthreads();
        part[tid] += t;
        __syncthreads();
    }
    int run = (tid == 0) ? 0 : part[tid - 1];
    #pragma unroll
    for (int i = 0; i < 8; ++i) {
        offs[base + i] = run;
        cursor[base + i] = run;
        run += v[i];
    }
    if (tid == 1023) offs[MTOT] = run;
}

__global__ void scatter_edges(const int* __restrict__ src, const int* __restrict__ dst,
                              int* __restrict__ cursor, int* __restrict__ csr_src, int E) {
    int i = blockIdx.x * 256 + threadIdx.x;
    if (i < E) {
        int p = atomicAdd(&cursor[dst[i]], 1);
        csr_src[p] = src[i];
    }
}

__global__ __launch_bounds__(256) void prep_convert(
    const float* __restrict__ W0, const float* __restrict__ W1,
    const float* __restrict__ W2, const float* __restrict__ W3,
    const float* __restrict__ W4, const float* __restrict__ W5,
    unsigned short* __restrict__ wtbase,
    const float* __restrict__ X,
    unsigned short* __restrict__ Ahi, unsigned short* __restrict__ Alo,
    int* __restrict__ deg)
{
    int z = blockIdx.z;
    if (z == 7) {
        if (blockIdx.x == 0 && blockIdx.y == 0)
            for (int i = threadIdx.x; i < MTOT; i += 256) deg[i] = 0;
        return;
    }
    if (z == 6) {
        int bid = blockIdx.x * 16 + blockIdx.y;
        int t0 = bid * 256 + threadIdx.x;
        #pragma unroll
        for (int it = 0; it < 16; ++it) {
            int i = (t0 + it * 65536) * 4;
            float4 vv = *(const float4*)(X + i);
            ushort4 h, l;
            h.x = f2bf(vv.x); l.x = f2bf(vv.x - bf2f(h.x));
            h.y = f2bf(vv.y); l.y = f2bf(vv.y - bf2f(h.y));
            h.z = f2bf(vv.z); l.z = f2bf(vv.z - bf2f(h.z));
            h.w = f2bf(vv.w); l.w = f2bf(vv.w - bf2f(h.w));
            *(ushort4*)(Ahi + i) = h;
            *(ushort4*)(Alo + i) = l;
        }
        return;
    }
    const float* W = (z == 0) ? W0 : (z == 1) ? W1 : (z == 2) ? W2
                   : (z == 3) ? W3 : (z == 4) ? W4 : W5;
    int L = z >> 1, lr = z & 1;
    const size_t SZ = (size_t)HD * HD;
    unsigned short* Whi = wtbase + (L * 4 + lr * 2) * SZ;
    unsigned short* Wlo = Whi + SZ;

    __shared__ float t[32][33];
    int bx = blockIdx.x * 32;
    int by = blockIdx.y * 32;
    int tx = threadIdx.x & 31, ty = threadIdx.x >> 5;
    for (int i = ty; i < 32; i += 8)
        t[i][tx] = W[(size_t)(by + i) * HD + bx + tx];
    __syncthreads();
    for (int i = ty; i < 32; i += 8) {
        float vv = t[tx][i];
        unsigned short h = f2bf(vv);
        unsigned short l = f2bf(vv - bf2f(h));
        Whi[(size_t)(bx + i) * HD + by + tx] = h;
        Wlo[(size_t)(bx + i) * HD + by + tx] = l;
    }
}

// ================= split-bf16 MFMA dual GEMM (m97 structure) =================

__global__ __launch_bounds__(256) void gemm_mfma_dual(
    const unsigned short* __restrict__ Ahi, const unsigned short* __restrict__ Alo,
    const unsigned short* __restrict__ Bhi_l, const unsigned short* __restrict__ Blo_l,
    const unsigned short* __restrict__ Bhi_r, const unsigned short* __restrict__ Blo_r,
    const float* __restrict__ bias_l, const float* __restrict__ bias_r,
    float* __restrict__ Cl, float* __restrict__ Cr)
{
    const unsigned short* Bhi = blockIdx.z ? Bhi_r : Bhi_l;
    const unsigned short* Blo = blockIdx.z ? Blo_r : Blo_l;
    const float* bias         = blockIdx.z ? bias_r : bias_l;
    float* C                  = blockIdx.z ? Cr : Cl;

    __shared__ __align__(16) unsigned short lds[4 * 128 * 32];

    int tid = threadIdx.x;
    int wave = tid >> 6, lane = tid & 63;
    int bm = blockIdx.y * 128, bn = blockIdx.x * 128;

    const unsigned short* gsrc[4] = {Ahi, Alo, Bhi, Blo};
    int rowbase[4] = {bm, bm, bn, bn};

    const unsigned short* gbase =
        gsrc[wave] + (size_t)(rowbase[wave] + (lane >> 2)) * 512 + (lane & 3) * 8;

    floatx4 acc[4][4] = {};

    int wm = wave & 1, wn = wave >> 1;
    int lr = lane & 15, lq = lane >> 4;

    for (int k0 = 0; k0 < 512; k0 += 32) {
        const unsigned short* g = gbase + k0;
        #pragma unroll
        for (int rg = 0; rg < 8; ++rg) {
            __builtin_amdgcn_global_load_lds(
                (const __attribute__((address_space(1))) unsigned int*)(g + (size_t)rg * 16 * 512),
                (__attribute__((address_space(3))) unsigned int*)(&lds[wave * 4096 + rg * 512]),
                16, 0, 0);
        }
        __syncthreads();

        bf16x8 ah[4], al[4], bh[4], bl_[4];
        #pragma unroll
        for (int i = 0; i < 4; ++i) {
            int mrow = wm * 64 + i * 16 + lr;
            ah[i]  = *(const bf16x8*)&lds[0 * 4096 + mrow * 32 + lq * 8];
            al[i]  = *(const bf16x8*)&lds[1 * 4096 + mrow * 32 + lq * 8];
            int nrow = wn * 64 + i * 16 + lr;
            bh[i]  = *(const bf16x8*)&lds[2 * 4096 + nrow * 32 + lq * 8];
            bl_[i] = *(const bf16x8*)&lds[3 * 4096 + nrow * 32 + lq * 8];
        }
        #pragma unroll
        for (int i = 0; i < 4; ++i)
            #pragma unroll
            for (int j = 0; j < 4; ++j) {
                acc[i][j] = __builtin_amdgcn_mfma_f32_16x16x32_bf16(ah[i], bh[j],  acc[i][j], 0, 0, 0);
                acc[i][j] = __builtin_amdgcn_mfma_f32_16x16x32_bf16(ah[i], bl_[j], acc[i][j], 0, 0, 0);
                acc[i][j] = __builtin_amdgcn_mfma_f32_16x16x32_bf16(al[i], bh[j],  acc[i][j], 0, 0, 0);
            }
        __syncthreads();
    }

    #pragma unroll
    for (int j = 0; j < 4; ++j) {
        int n = bn + wn * 64 + j * 16 + lr;
        float bv = bias[n];
        #pragma unroll
        for (int i = 0; i < 4; ++i) {
            int mbase = bm + wm * 64 + i * 16 + lq * 4;
            #pragma unroll
            for (int r = 0; r < 4; ++r)
                C[(size_t)(mbase + r) * 512 + n] = acc[i][j][r] + bv;
        }
    }
}

// ================= fused aggregation v3 =================
// Block = 512 thr (8 waves) per 4 nodes, XCD-swizzled.
// vs r8: (a) CSR idx preloaded to LDS (removes global idx load from both
// per-edge chains); (b) scores via a·lrelu(t) = 0.6·Σa·t + 0.4·Σa·|t|
// (abs is a free VOP3 modifier -> 3 VALU/feature instead of 4).

__global__ __launch_bounds__(512) void gat_fused3(
    const float* __restrict__ xl, const float* __restrict__ xr,
    const float* __restrict__ avec, const float* __restrict__ bias,
    const int* __restrict__ offs, const int* __restrict__ csr_src,
    float* __restrict__ out, unsigned short* __restrict__ Ohi,
    unsigned short* __restrict__ Olo, int write_fp32)
{
    __shared__ float xr_sh[4][512];   // 8 KB
    __shared__ float sc_sh[4][128];   // 2 KB
    __shared__ int   idx_sh[4][128];  // 2 KB
    __shared__ float inv_sh[4];

    int gid = blockIdx.x;
    int nbase = ((gid & 7) << 10) + ((gid >> 3) << 2);
    int tid = threadIdx.x;
    int wv = tid >> 6, lane = tid & 63;

    int o0 = offs[nbase], o1 = offs[nbase + 1], o2 = offs[nbase + 2];
    int o3 = offs[nbase + 3], o4 = offs[nbase + 4];

    // phase 0a: preload xr rows (512 thr x 1 float4)
    {
        int row = tid >> 7, col = tid & 127;
        *(float4*)&xr_sh[row][col * 4] =
            *(const float4*)(xr + (size_t)(nbase + row) * HD + col * 4);
    }
    // phase 0b: preload csr indices (waves 0-3, one node each)
    if (wv < 4) {
        int nb = (wv == 0) ? o0 : (wv == 1) ? o1 : (wv == 2) ? o2 : o3;
        int ne = (wv == 0) ? o1 : (wv == 1) ? o2 : (wv == 2) ? o3 : o4;
        int dg = ne - nb; if (dg > 128) dg = 128;
        for (int i = lane; i < dg; i += 64) idx_sh[wv][i] = csr_src[nb + i];
    }
    __syncthreads();

    // phase 1: pooled edge scores (16 lanes/edge, 4 edges/wave-iter)
    {
        int sub = lane >> 4, flane = lane & 15;
        float4 av[8];
        #pragma unroll
        for (int i = 0; i < 8; ++i)
            av[i] = *(const float4*)(avec + i * 64 + flane * 4);

        for (int p0 = o0 + wv * 4; p0 < o4; p0 += 32) {
            int p = p0 + sub;
            bool valid = p < o4;
            int pc = valid ? p : o0;
            int nid = (pc >= o1) + (pc >= o2) + (pc >= o3);
            int nb = (nid == 0) ? o0 : (nid == 1) ? o1 : (nid == 2) ? o2 : o3;
            int local = pc - nb;
            valid = valid && (local < 128);
            int j = idx_sh[nid][valid ? local : 0];
            const float* xls = xl + (size_t)j * HD;
            float pe0 = 0.f, pe1 = 0.f;
            #pragma unroll
            for (int i = 0; i < 8; ++i) {
                float4 xv = *(const float4*)(xls + i * 64 + flane * 4);
                float4 rv = *(const float4*)&xr_sh[nid][i * 64 + flane * 4];
                float t;
                t = xv.x + rv.x; pe0 = fmaf(av[i].x, t, pe0); pe1 = fmaf(av[i].x, fabsf(t), pe1);
                t = xv.y + rv.y; pe0 = fmaf(av[i].y, t, pe0); pe1 = fmaf(av[i].y, fabsf(t), pe1);
                t = xv.z + rv.z; pe0 = fmaf(av[i].z, t, pe0); pe1 = fmaf(av[i].z, fabsf(t), pe1);
                t = xv.w + rv.w; pe0 = fmaf(av[i].w, t, pe0); pe1 = fmaf(av[i].w, fabsf(t), pe1);
            }
            float pe = fmaf(0.6f, pe0, 0.4f * pe1);   // == a . leaky_relu(., 0.2)
            pe += __shfl_xor(pe, 1, 64);
            pe += __shfl_xor(pe, 2, 64);
            pe += __shfl_xor(pe, 4, 64);
            pe += __shfl_xor(pe, 8, 64);
            if (valid && flane == 0) sc_sh[nid][local] = pe;
        }
    }
    __syncthreads();

    // phase 2: softmax per node (waves 0-3)
    if (wv < 4) {
        int nb = (wv == 0) ? o0 : (wv == 1) ? o1 : (wv == 2) ? o2 : o3;
        int ne = (wv == 0) ? o1 : (wv == 1) ? o2 : (wv == 2) ? o3 : o4;
        int dg = ne - nb; if (dg > 128) dg = 128;
        float s0v = (lane < dg) ? sc_sh[wv][lane] : -1e30f;
        float s1v = (lane + 64 < dg) ? sc_sh[wv][lane + 64] : -1e30f;
        float m = fmaxf(s0v, s1v);
        #pragma unroll
        for (int off = 32; off; off >>= 1) m = fmaxf(m, __shfl_xor(m, off, 64));
        float e0 = (lane < dg) ? __expf(s0v - m) : 0.f;
        float e1 = (lane + 64 < dg) ? __expf(s1v - m) : 0.f;
        if (lane < dg) sc_sh[wv][lane] = e0;
        if (lane + 64 < dg) sc_sh[wv][lane + 64] = e1;
        float s = e0 + e1;
        #pragma unroll
        for (int off = 32; off; off >>= 1) s += __shfl_xor(s, off, 64);
        if (lane == 0) inv_sh[wv] = (s > 0.f) ? 1.f / s : 0.f;
    }
    __syncthreads();

    // phase 3: weighted gather, one wave per (node, feature-half), ILP-8
    int nid = wv & 3, half = wv >> 2;
    int node = nbase + nid;
    int nb = (nid == 0) ? o0 : (nid == 1) ? o1 : (nid == 2) ? o2 : o3;
    int ne = (nid == 0) ? o1 : (nid == 1) ? o2 : (nid == 2) ? o3 : o4;
    int dg = ne - nb; if (dg > 128) dg = 128;
    int hb = half * 256 + lane * 4;

    float4 acc = {0.f, 0.f, 0.f, 0.f};
    int p = 0;
    for (; p + 8 <= dg; p += 8) {
        float w[8]; const float* q[8];
        #pragma unroll
        for (int u = 0; u < 8; ++u) {
            w[u] = sc_sh[nid][p + u];
            q[u] = xl + (size_t)idx_sh[nid][p + u] * HD + hb;
        }
        float4 x[8];
        #pragma unroll
        for (int u = 0; u < 8; ++u) x[u] = *(const float4*)q[u];
        #pragma unroll
        for (int u = 0; u < 8; ++u) {
            acc.x += w[u] * x[u].x; acc.y += w[u] * x[u].y;
            acc.z += w[u] * x[u].z; acc.w += w[u] * x[u].w;
        }
    }
    for (; p < dg; ++p) {
        float w = sc_sh[nid][p];
        const float* q = xl + (size_t)idx_sh[nid][p] * HD + hb;
        float4 x = *(const float4*)q;
        acc.x += w * x.x; acc.y += w * x.y; acc.z += w * x.z; acc.w += w * x.w;
    }

    float inv = inv_sh[nid];
    float4 bv = *(const float4*)(bias + hb);
    float4 o = {acc.x * inv + bv.x, acc.y * inv + bv.y,
                acc.z * inv + bv.z, acc.w * inv + bv.w};

    if (write_fp32) {
        *(float4*)(out + (size_t)node * HD + hb) = o;
    } else {
        size_t rb = (size_t)node * HD + hb;
        ushort4 h, lo;
        h.x = f2bf(o.x); lo.x = f2bf(o.x - bf2f(h.x));
        h.y = f2bf(o.y); lo.y = f2bf(o.y - bf2f(h.y));
        h.z = f2bf(o.z); lo.z = f2bf(o.z - bf2f(h.z));
        h.w = f2bf(o.w); lo.w = f2bf(o.w - bf2f(h.w));
        *(ushort4*)(Ohi + rb) = h;
        *(ushort4*)(Olo + rb) = lo;
    }
}

// ---------------- launch ----------------

extern "C" void kernel_launch(void* const* d_in, const int* in_sizes, int n_in,
                              void* d_out, int out_size, void* d_ws, size_t ws_size,
                              hipStream_t stream) {
    const float* x0 = (const float*)d_in[0];
    const int* eidx = (const int*)d_in[2];
    int E = in_sizes[2] / 2;
    const int* esrc = eidx;
    const int* edst = eidx + E;

    const float* Wl[3] = {(const float*)d_in[3],  (const float*)d_in[9],  (const float*)d_in[15]};
    const float* bl[3] = {(const float*)d_in[4],  (const float*)d_in[10], (const float*)d_in[16]};
    const float* Wr[3] = {(const float*)d_in[5],  (const float*)d_in[11], (const float*)d_in[17]};
    const float* br[3] = {(const float*)d_in[6],  (const float*)d_in[12], (const float*)d_in[18]};
    const float* av[3] = {(const float*)d_in[7],  (const float*)d_in[13], (const float*)d_in[19]};
    const float* bs[3] = {(const float*)d_in[8],  (const float*)d_in[14], (const float*)d_in[20]};

    char* w = (char*)d_ws;
    unsigned short* Ahi = (unsigned short*)w; w += (size_t)MTOT * HD * 2;
    unsigned short* Alo = (unsigned short*)w; w += (size_t)MTOT * HD * 2;
    unsigned short* wtbase = (unsigned short*)w; w += 12 * (size_t)HD * HD * 2;
    float* xl = (float*)w; w += (size_t)MTOT * HD * 4;
    float* xr = (float*)w; w += (size_t)MTOT * HD * 4;
    int* deg    = (int*)w;
    int* offs   = deg + MTOT;
    int* cursor = offs + MTOT + 8;
    int* csr    = cursor + MTOT;
    const size_t SZ = (size_t)HD * HD;

    PrepParams P;
    P.W6[0] = Wl[0]; P.W6[1] = Wr[0]; P.W6[2] = Wl[1];
    P.W6[3] = Wr[1]; P.W6[4] = Wl[2]; P.W6[5] = Wr[2];
    P.x0 = x0; P.wtbase = wtbase; P.Ahi = Ahi; P.Alo = Alo;
    P.esrc = esrc; P.edst = edst; P.E = E;
    P.deg = deg; P.offs = offs; P.cursor = cursor; P.csr = csr;

    void* args[] = {(void*)&P};
    hipError_t err = hipLaunchCooperativeKernel((const void*)prep_csr,
                                                dim3(256), dim3(256), args, 0, stream);
    if (err != hipSuccess) {
        // fallback: r8 multi-dispatch prep + CSR
        prep_convert<<<dim3(16, 16, 8), 256, 0, stream>>>(
            Wl[0], Wr[0], Wl[1], Wr[1], Wl[2], Wr[2], wtbase, x0, Ahi, Alo, deg);
        count_deg<<<(E + 255) / 256, 256, 0, stream>>>(edst, deg, E);
        scan_offsets<<<1, 1024, 0, stream>>>(deg, offs, cursor);
        scatter_edges<<<(E + 255) / 256, 256, 0, stream>>>(esrc, edst, cursor, csr, E);
    }

    dim3 ggrid(HD / 128, MTOT / 128, 2);
    for (int L = 0; L < 3; ++L) {
        gemm_mfma_dual<<<ggrid, 256, 0, stream>>>(Ahi, Alo,
            wtbase + (L * 4 + 0) * SZ, wtbase + (L * 4 + 1) * SZ,
            wtbase + (L * 4 + 2) * SZ, wtbase + (L * 4 + 3) * SZ,
            bl[L], br[L], xl, xr);
        int last = (L == 2);
        gat_fused3<<<MTOT / 4, 512, 0, stream>>>(xl, xr, av[L], bs[L], offs, csr,
                                                 last ? (float*)d_out : nullptr,
                                                 last ? nullptr : Ahi,
                                                 last ? nullptr : Alo,
                                                 last);
    }
}

// Round 11
// 336.080 us; speedup vs baseline: 2.9429x; 1.4321x over previous
//
#include <hip/hip_runtime.h>
#include <math.h>

#define MTOT 8192   // B*N
#define HD   512    // hidden dim

typedef __attribute__((ext_vector_type(8))) short bf16x8;
typedef __attribute__((ext_vector_type(4))) float floatx4;

__device__ inline unsigned short f2bf(float f) {
    unsigned int u = __float_as_uint(f);
    unsigned int r = (u + 0x7FFFu + ((u >> 16) & 1u)) >> 16;
    return (unsigned short)r;
}
__device__ inline float bf2f(unsigned short h) {
    return __uint_as_float(((unsigned int)h) << 16);
}

// ---------------- CSR build (grid-parallel, multi-dispatch) ----------------
// NOTE: r6/r9/r10 lessons — single-block LDS builds and cooperative grid.sync
// variants are 10-40x slower than this plain 3-dispatch chain. grid.sync on
// MI355X costs ~35us each regardless of dirty-set size; a dispatch boundary
// is ~5-8us. Do not re-fuse.

__global__ void count_deg(const int* __restrict__ dst, int* __restrict__ deg, int E) {
    int i = blockIdx.x * 256 + threadIdx.x;
    if (i < E) atomicAdd(&deg[dst[i]], 1);
}

__global__ __launch_bounds__(1024) void scan_offsets(const int* __restrict__ deg,
                                                     int* __restrict__ offs,
                                                     int* __restrict__ cursor) {
    __shared__ int part[1024];
    int tid = threadIdx.x;
    int base = tid * 8;
    int v[8]; int s = 0;
    #pragma unroll
    for (int i = 0; i < 8; ++i) { v[i] = deg[base + i]; s += v[i]; }
    part[tid] = s;
    __syncthreads();
    for (int off = 1; off < 1024; off <<= 1) {
        int t = (tid >= off) ? part[tid - off] : 0;
        __syncthreads();
        part[tid] += t;
        __syncthreads();
    }
    int run = (tid == 0) ? 0 : part[tid - 1];
    #pragma unroll
    for (int i = 0; i < 8; ++i) {
        offs[base + i] = run;
        cursor[base + i] = run;
        run += v[i];
    }
    if (tid == 1023) offs[MTOT] = run;
}

__global__ void scatter_edges(const int* __restrict__ src, const int* __restrict__ dst,
                              int* __restrict__ cursor, int* __restrict__ csr_src, int E) {
    int i = blockIdx.x * 256 + threadIdx.x;
    if (i < E) {
        int p = atomicAdd(&cursor[dst[i]], 1);
        csr_src[p] = src[i];
    }
}

// ---------------- combined weight + activation split + deg zero ----------------
// z in [0,6): weight matrix z. z == 6: activation split. z == 7: zero deg.

__global__ __launch_bounds__(256) void prep_convert(
    const float* __restrict__ W0, const float* __restrict__ W1,
    const float* __restrict__ W2, const float* __restrict__ W3,
    const float* __restrict__ W4, const float* __restrict__ W5,
    unsigned short* __restrict__ wtbase,
    const float* __restrict__ X,
    unsigned short* __restrict__ Ahi, unsigned short* __restrict__ Alo,
    int* __restrict__ deg)
{
    int z = blockIdx.z;
    if (z == 7) {
        if (blockIdx.x == 0 && blockIdx.y == 0)
            for (int i = threadIdx.x; i < MTOT; i += 256) deg[i] = 0;
        return;
    }
    if (z == 6) {
        int bid = blockIdx.x * 16 + blockIdx.y;       // 0..255
        int t0 = bid * 256 + threadIdx.x;             // 0..65535
        #pragma unroll
        for (int it = 0; it < 16; ++it) {
            int i = (t0 + it * 65536) * 4;
            float4 vv = *(const float4*)(X + i);
            ushort4 h, l;
            h.x = f2bf(vv.x); l.x = f2bf(vv.x - bf2f(h.x));
            h.y = f2bf(vv.y); l.y = f2bf(vv.y - bf2f(h.y));
            h.z = f2bf(vv.z); l.z = f2bf(vv.z - bf2f(h.z));
            h.w = f2bf(vv.w); l.w = f2bf(vv.w - bf2f(h.w));
            *(ushort4*)(Ahi + i) = h;
            *(ushort4*)(Alo + i) = l;
        }
        return;
    }
    const float* W = (z == 0) ? W0 : (z == 1) ? W1 : (z == 2) ? W2
                   : (z == 3) ? W3 : (z == 4) ? W4 : W5;
    int L = z >> 1, lr = z & 1;
    const size_t SZ = (size_t)HD * HD;
    unsigned short* Whi = wtbase + (L * 4 + lr * 2) * SZ;
    unsigned short* Wlo = Whi + SZ;

    __shared__ float t[32][33];
    int bx = blockIdx.x * 32;  // n base
    int by = blockIdx.y * 32;  // k base
    int tx = threadIdx.x & 31, ty = threadIdx.x >> 5;
    for (int i = ty; i < 32; i += 8)
        t[i][tx] = W[(size_t)(by + i) * HD + bx + tx];
    __syncthreads();
    for (int i = ty; i < 32; i += 8) {
        float vv = t[tx][i];
        unsigned short h = f2bf(vv);
        unsigned short l = f2bf(vv - bf2f(h));
        Whi[(size_t)(bx + i) * HD + by + tx] = h;
        Wlo[(size_t)(bx + i) * HD + by + tx] = l;
    }
}

// ---------------- split-bf16 MFMA dual GEMM (m97 structure) ----------------
// ~31us/dispatch = at the m97-class throughput ceiling for this shape.

__global__ __launch_bounds__(256) void gemm_mfma_dual(
    const unsigned short* __restrict__ Ahi, const unsigned short* __restrict__ Alo,
    const unsigned short* __restrict__ Bhi_l, const unsigned short* __restrict__ Blo_l,
    const unsigned short* __restrict__ Bhi_r, const unsigned short* __restrict__ Blo_r,
    const float* __restrict__ bias_l, const float* __restrict__ bias_r,
    float* __restrict__ Cl, float* __restrict__ Cr)
{
    const unsigned short* Bhi = blockIdx.z ? Bhi_r : Bhi_l;
    const unsigned short* Blo = blockIdx.z ? Blo_r : Blo_l;
    const float* bias         = blockIdx.z ? bias_r : bias_l;
    float* C                  = blockIdx.z ? Cr : Cl;

    __shared__ __align__(16) unsigned short lds[4 * 128 * 32];

    int tid = threadIdx.x;
    int wave = tid >> 6, lane = tid & 63;
    int bm = blockIdx.y * 128, bn = blockIdx.x * 128;

    const unsigned short* gsrc[4] = {Ahi, Alo, Bhi, Blo};
    int rowbase[4] = {bm, bm, bn, bn};

    const unsigned short* gbase =
        gsrc[wave] + (size_t)(rowbase[wave] + (lane >> 2)) * 512 + (lane & 3) * 8;

    floatx4 acc[4][4] = {};

    int wm = wave & 1, wn = wave >> 1;
    int lr = lane & 15, lq = lane >> 4;

    for (int k0 = 0; k0 < 512; k0 += 32) {
        const unsigned short* g = gbase + k0;
        #pragma unroll
        for (int rg = 0; rg < 8; ++rg) {
            __builtin_amdgcn_global_load_lds(
                (const __attribute__((address_space(1))) unsigned int*)(g + (size_t)rg * 16 * 512),
                (__attribute__((address_space(3))) unsigned int*)(&lds[wave * 4096 + rg * 512]),
                16, 0, 0);
        }
        __syncthreads();

        bf16x8 ah[4], al[4], bh[4], bl_[4];
        #pragma unroll
        for (int i = 0; i < 4; ++i) {
            int mrow = wm * 64 + i * 16 + lr;
            ah[i]  = *(const bf16x8*)&lds[0 * 4096 + mrow * 32 + lq * 8];
            al[i]  = *(const bf16x8*)&lds[1 * 4096 + mrow * 32 + lq * 8];
            int nrow = wn * 64 + i * 16 + lr;
            bh[i]  = *(const bf16x8*)&lds[2 * 4096 + nrow * 32 + lq * 8];
            bl_[i] = *(const bf16x8*)&lds[3 * 4096 + nrow * 32 + lq * 8];
        }
        #pragma unroll
        for (int i = 0; i < 4; ++i)
            #pragma unroll
            for (int j = 0; j < 4; ++j) {
                acc[i][j] = __builtin_amdgcn_mfma_f32_16x16x32_bf16(ah[i], bh[j],  acc[i][j], 0, 0, 0);
                acc[i][j] = __builtin_amdgcn_mfma_f32_16x16x32_bf16(ah[i], bl_[j], acc[i][j], 0, 0, 0);
                acc[i][j] = __builtin_amdgcn_mfma_f32_16x16x32_bf16(al[i], bh[j],  acc[i][j], 0, 0, 0);
            }
        __syncthreads();
    }

    #pragma unroll
    for (int j = 0; j < 4; ++j) {
        int n = bn + wn * 64 + j * 16 + lr;
        float bv = bias[n];
        #pragma unroll
        for (int i = 0; i < 4; ++i) {
            int mbase = bm + wm * 64 + i * 16 + lq * 4;
            #pragma unroll
            for (int r = 0; r < 4; ++r)
                C[(size_t)(mbase + r) * 512 + n] = acc[i][j][r] + bv;
        }
    }
}

// ---------------- fused aggregation v3 ----------------
// Block = 512 thr (8 waves) per 4 nodes, XCD-swizzled (graph g -> XCD g).
// CSR idx preloaded to LDS; lrelu via a·lrelu(t) = 0.6·Σa·t + 0.4·Σa·|t|.

__global__ __launch_bounds__(512) void gat_fused3(
    const float* __restrict__ xl, const float* __restrict__ xr,
    const float* __restrict__ avec, const float* __restrict__ bias,
    const int* __restrict__ offs, const int* __restrict__ csr_src,
    float* __restrict__ out, unsigned short* __restrict__ Ohi,
    unsigned short* __restrict__ Olo, int write_fp32)
{
    __shared__ float xr_sh[4][512];   // 8 KB
    __shared__ float sc_sh[4][128];   // 2 KB
    __shared__ int   idx_sh[4][128];  // 2 KB
    __shared__ float inv_sh[4];

    int gid = blockIdx.x;
    int nbase = ((gid & 7) << 10) + ((gid >> 3) << 2);
    int tid = threadIdx.x;
    int wv = tid >> 6, lane = tid & 63;

    int o0 = offs[nbase], o1 = offs[nbase + 1], o2 = offs[nbase + 2];
    int o3 = offs[nbase + 3], o4 = offs[nbase + 4];

    // phase 0a: preload xr rows (512 thr x 1 float4)
    {
        int row = tid >> 7, col = tid & 127;
        *(float4*)&xr_sh[row][col * 4] =
            *(const float4*)(xr + (size_t)(nbase + row) * HD + col * 4);
    }
    // phase 0b: preload csr indices (waves 0-3, one node each)
    if (wv < 4) {
        int nb = (wv == 0) ? o0 : (wv == 1) ? o1 : (wv == 2) ? o2 : o3;
        int ne = (wv == 0) ? o1 : (wv == 1) ? o2 : (wv == 2) ? o3 : o4;
        int dg = ne - nb; if (dg > 128) dg = 128;
        for (int i = lane; i < dg; i += 64) idx_sh[wv][i] = csr_src[nb + i];
    }
    __syncthreads();

    // phase 1: pooled edge scores (16 lanes/edge, 4 edges/wave-iter)
    {
        int sub = lane >> 4, flane = lane & 15;
        float4 av[8];
        #pragma unroll
        for (int i = 0; i < 8; ++i)
            av[i] = *(const float4*)(avec + i * 64 + flane * 4);

        for (int p0 = o0 + wv * 4; p0 < o4; p0 += 32) {
            int p = p0 + sub;
            bool valid = p < o4;
            int pc = valid ? p : o0;
            int nid = (pc >= o1) + (pc >= o2) + (pc >= o3);
            int nb = (nid == 0) ? o0 : (nid == 1) ? o1 : (nid == 2) ? o2 : o3;
            int local = pc - nb;
            valid = valid && (local < 128);
            int j = idx_sh[nid][valid ? local : 0];
            const float* xls = xl + (size_t)j * HD;
            float pe0 = 0.f, pe1 = 0.f;
            #pragma unroll
            for (int i = 0; i < 8; ++i) {
                float4 xv = *(const float4*)(xls + i * 64 + flane * 4);
                float4 rv = *(const float4*)&xr_sh[nid][i * 64 + flane * 4];
                float t;
                t = xv.x + rv.x; pe0 = fmaf(av[i].x, t, pe0); pe1 = fmaf(av[i].x, fabsf(t), pe1);
                t = xv.y + rv.y; pe0 = fmaf(av[i].y, t, pe0); pe1 = fmaf(av[i].y, fabsf(t), pe1);
                t = xv.z + rv.z; pe0 = fmaf(av[i].z, t, pe0); pe1 = fmaf(av[i].z, fabsf(t), pe1);
                t = xv.w + rv.w; pe0 = fmaf(av[i].w, t, pe0); pe1 = fmaf(av[i].w, fabsf(t), pe1);
            }
            float pe = fmaf(0.6f, pe0, 0.4f * pe1);   // == a . leaky_relu(., 0.2)
            pe += __shfl_xor(pe, 1, 64);
            pe += __shfl_xor(pe, 2, 64);
            pe += __shfl_xor(pe, 4, 64);
            pe += __shfl_xor(pe, 8, 64);
            if (valid && flane == 0) sc_sh[nid][local] = pe;
        }
    }
    __syncthreads();

    // phase 2: softmax per node (waves 0-3)
    if (wv < 4) {
        int nb = (wv == 0) ? o0 : (wv == 1) ? o1 : (wv == 2) ? o2 : o3;
        int ne = (wv == 0) ? o1 : (wv == 1) ? o2 : (wv == 2) ? o3 : o4;
        int dg = ne - nb; if (dg > 128) dg = 128;
        float s0v = (lane < dg) ? sc_sh[wv][lane] : -1e30f;
        float s1v = (lane + 64 < dg) ? sc_sh[wv][lane + 64] : -1e30f;
        float m = fmaxf(s0v, s1v);
        #pragma unroll
        for (int off = 32; off; off >>= 1) m = fmaxf(m, __shfl_xor(m, off, 64));
        float e0 = (lane < dg) ? __expf(s0v - m) : 0.f;
        float e1 = (lane + 64 < dg) ? __expf(s1v - m) : 0.f;
        if (lane < dg) sc_sh[wv][lane] = e0;
        if (lane + 64 < dg) sc_sh[wv][lane + 64] = e1;
        float s = e0 + e1;
        #pragma unroll
        for (int off = 32; off; off >>= 1) s += __shfl_xor(s, off, 64);
        if (lane == 0) inv_sh[wv] = (s > 0.f) ? 1.f / s : 0.f;
    }
    __syncthreads();

    // phase 3: weighted gather, one wave per (node, feature-half), ILP-8
    int nid = wv & 3, half = wv >> 2;
    int node = nbase + nid;
    int nb = (nid == 0) ? o0 : (nid == 1) ? o1 : (nid == 2) ? o2 : o3;
    int ne = (nid == 0) ? o1 : (nid == 1) ? o2 : (nid == 2) ? o3 : o4;
    int dg = ne - nb; if (dg > 128) dg = 128;
    int hb = half * 256 + lane * 4;

    float4 acc = {0.f, 0.f, 0.f, 0.f};
    int p = 0;
    for (; p + 8 <= dg; p += 8) {
        float w[8]; const float* q[8];
        #pragma unroll
        for (int u = 0; u < 8; ++u) {
            w[u] = sc_sh[nid][p + u];
            q[u] = xl + (size_t)idx_sh[nid][p + u] * HD + hb;
        }
        float4 x[8];
        #pragma unroll
        for (int u = 0; u < 8; ++u) x[u] = *(const float4*)q[u];
        #pragma unroll
        for (int u = 0; u < 8; ++u) {
            acc.x += w[u] * x[u].x; acc.y += w[u] * x[u].y;
            acc.z += w[u] * x[u].z; acc.w += w[u] * x[u].w;
        }
    }
    for (; p < dg; ++p) {
        float w = sc_sh[nid][p];
        const float* q = xl + (size_t)idx_sh[nid][p] * HD + hb;
        float4 x = *(const float4*)q;
        acc.x += w * x.x; acc.y += w * x.y; acc.z += w * x.z; acc.w += w * x.w;
    }

    float inv = inv_sh[nid];
    float4 bv = *(const float4*)(bias + hb);
    float4 o = {acc.x * inv + bv.x, acc.y * inv + bv.y,
                acc.z * inv + bv.z, acc.w * inv + bv.w};

    if (write_fp32) {
        *(float4*)(out + (size_t)node * HD + hb) = o;
    } else {
        size_t rb = (size_t)node * HD + hb;
        ushort4 h, lo;
        h.x = f2bf(o.x); lo.x = f2bf(o.x - bf2f(h.x));
        h.y = f2bf(o.y); lo.y = f2bf(o.y - bf2f(h.y));
        h.z = f2bf(o.z); lo.z = f2bf(o.z - bf2f(h.z));
        h.w = f2bf(o.w); lo.w = f2bf(o.w - bf2f(h.w));
        *(ushort4*)(Ohi + rb) = h;
        *(ushort4*)(Olo + rb) = lo;
    }
}

// ---------------- launch ----------------

extern "C" void kernel_launch(void* const* d_in, const int* in_sizes, int n_in,
                              void* d_out, int out_size, void* d_ws, size_t ws_size,
                              hipStream_t stream) {
    const float* x0 = (const float*)d_in[0];
    const int* eidx = (const int*)d_in[2];
    int E = in_sizes[2] / 2;
    const int* esrc = eidx;
    const int* edst = eidx + E;

    const float* Wl[3] = {(const float*)d_in[3],  (const float*)d_in[9],  (const float*)d_in[15]};
    const float* bl[3] = {(const float*)d_in[4],  (const float*)d_in[10], (const float*)d_in[16]};
    const float* Wr[3] = {(const float*)d_in[5],  (const float*)d_in[11], (const float*)d_in[17]};
    const float* br[3] = {(const float*)d_in[6],  (const float*)d_in[12], (const float*)d_in[18]};
    const float* av[3] = {(const float*)d_in[7],  (const float*)d_in[13], (const float*)d_in[19]};
    const float* bs[3] = {(const float*)d_in[8],  (const float*)d_in[14], (const float*)d_in[20]};

    char* w = (char*)d_ws;
    unsigned short* Ahi = (unsigned short*)w; w += (size_t)MTOT * HD * 2;
    unsigned short* Alo = (unsigned short*)w; w += (size_t)MTOT * HD * 2;
    unsigned short* wtbase = (unsigned short*)w; w += 12 * (size_t)HD * HD * 2;
    float* xl = (float*)w; w += (size_t)MTOT * HD * 4;
    float* xr = (float*)w; w += (size_t)MTOT * HD * 4;
    int* deg    = (int*)w;
    int* offs   = deg + MTOT;
    int* cursor = offs + MTOT + 8;
    int* csr    = cursor + MTOT;
    const size_t SZ = (size_t)HD * HD;

    prep_convert<<<dim3(16, 16, 8), 256, 0, stream>>>(
        Wl[0], Wr[0], Wl[1], Wr[1], Wl[2], Wr[2], wtbase, x0, Ahi, Alo, deg);
    count_deg<<<(E + 255) / 256, 256, 0, stream>>>(edst, deg, E);
    scan_offsets<<<1, 1024, 0, stream>>>(deg, offs, cursor);
    scatter_edges<<<(E + 255) / 256, 256, 0, stream>>>(esrc, edst, cursor, csr, E);

    dim3 ggrid(HD / 128, MTOT / 128, 2);
    for (int L = 0; L < 3; ++L) {
        gemm_mfma_dual<<<ggrid, 256, 0, stream>>>(Ahi, Alo,
            wtbase + (L * 4 + 0) * SZ, wtbase + (L * 4 + 1) * SZ,
            wtbase + (L * 4 + 2) * SZ, wtbase + (L * 4 + 3) * SZ,
            bl[L], br[L], xl, xr);
        int last = (L == 2);
        gat_fused3<<<MTOT / 4, 512, 0, stream>>>(xl, xr, av[L], bs[L], offs, csr,
                                                 last ? (float*)d_out : nullptr,
                                                 last ? nullptr : Ahi,
                                                 last ? nullptr : Alo,
                                                 last);
    }
}